// Round 12
// baseline (289.622 us; speedup 1.0000x reference)
//
#include <hip/hip_runtime.h>
#include <stdint.h>

#define DEVI __device__ __forceinline__

typedef __attribute__((ext_vector_type(8))) short bf16x8;
typedef __attribute__((ext_vector_type(4))) float f32x4;
typedef unsigned short u16;
typedef unsigned int u32;

#define TT 2049           // T+1
#define BH 32             // B*H
#define MPAD 8320         // 65*128
#define MREAL 8196        // 4*2049
#define NQ 8192           // 4*N_QKV
#define KDIM 256
#define VTP 2112          // padded t-stride for V^T

#define SBAR() __builtin_amdgcn_s_barrier()
#define MEMFENCE() asm volatile("" ::: "memory")
#define VMCNT(n) asm volatile("s_waitcnt vmcnt(" #n ")" ::: "memory")
#define LGKMCNT0() asm volatile("s_waitcnt lgkmcnt(0)" ::: "memory")

DEVI u16 f2bf(float f) {
    union { float f; u32 u; } v; v.f = f;
    u32 r = v.u + 0x7FFF + ((v.u >> 16) & 1);
    return (u16)(r >> 16);
}
DEVI float bf2f(u16 h) {
    union { u32 u; float f; } v; v.u = ((u32)h) << 16;
    return v.f;
}

#define GLD16(src, lds) __builtin_amdgcn_global_load_lds( \
    (const __attribute__((address_space(1))) void*)(src), \
    (__attribute__((address_space(3))) void*)(lds), 16, 0, 0)

// ---------------- conversion kernels (x4 vectorized) ----------------
__global__ void k_conv_x0(const float* __restrict__ x, const float* __restrict__ wsink,
                          u16* __restrict__ x0b) {
    int idx = blockIdx.x * 256 + threadIdx.x;
    if (idx >= MPAD * 64) return;
    int m = idx >> 6, c = (idx & 63) << 2;
    f32x4 v = {0.f, 0.f, 0.f, 0.f};
    if (m < MREAL) {
        int b = m / TT, t = m - b * TT;
        const float* src = (t == 0) ? (wsink + c) : (x + ((size_t)((b << 11) + t - 1) << 8) + c);
        v = *(const f32x4*)src;
    }
    union { u16 h[4]; uint2 u2; } o;
#pragma unroll
    for (int i = 0; i < 4; ++i) o.h[i] = f2bf(v[i]);
    *(uint2*)(x0b + ((size_t)idx << 2)) = o.u2;
}

__global__ void k_conv_bf16(const float* __restrict__ s, u16* __restrict__ d, int n4) {
    int idx = blockIdx.x * 256 + threadIdx.x;
    if (idx >= n4) return;
    f32x4 v = *(const f32x4*)(s + ((size_t)idx << 2));
    union { u16 h[4]; uint2 u2; } o;
#pragma unroll
    for (int i = 0; i < 4; ++i) o.h[i] = f2bf(v[i]);
    *(uint2*)(d + ((size_t)idx << 2)) = o.u2;
}

// ---------------- GEMM1: qkvg = x0 @ Wqkvg^T with in-register rope+rms epilogue ------
// (round-10 form, unchanged)
__global__ __launch_bounds__(512) void k_gemm_qkvg(const u16* __restrict__ A, const u16* __restrict__ Bm,
                                                   const float* __restrict__ cosb, const float* __restrict__ sinb,
                                                   const float* __restrict__ tao,
                                                   u16* __restrict__ Qb, u16* __restrict__ Kb,
                                                   u16* __restrict__ Vt, u16* __restrict__ Gb) {
    __shared__ __align__(16) u16 ldsA[128 * 64];      // 16KB
    __shared__ __align__(16) u16 ldsB[256 * 64];      // 32KB
    __shared__ float rowsum[128 * 4];                 // 2KB
    const int tid = threadIdx.x, l = tid & 63, w = tid >> 6;
    const int row0 = blockIdx.x * 128;
    const int gcol0 = blockIdx.y * 256;
    const int h = gcol0 >> 10, ty = (gcol0 & 1023) >> 8;
    const int mbase = (w >> 2) * 64, nw = w & 3;
    f32x4 acc[4][4];
    const f32x4 zero = {0.f, 0.f, 0.f, 0.f};
#pragma unroll
    for (int i = 0; i < 4; ++i)
#pragma unroll
        for (int j = 0; j < 4; ++j) acc[i][j] = zero;

    for (int kt = 0; kt < KDIM; kt += 64) {
        __syncthreads();
#pragma unroll
        for (int it = 0; it < 2; ++it) {      // A: 128 rows of 128B
            int lin = (it * 512 + tid) * 16;
            int r = lin >> 7, cb = lin & 127;
            int scb = cb ^ ((r & 7) << 4);
            GLD16((const char*)(A + (size_t)(row0 + r) * KDIM + kt) + scb,
                  (char*)ldsA + it * 8192 + w * 1024);
        }
#pragma unroll
        for (int it = 0; it < 4; ++it) {      // B: 256 rows of 128B
            int lin = (it * 512 + tid) * 16;
            int r = lin >> 7, cb = lin & 127;
            int scb = cb ^ ((r & 7) << 4);
            GLD16((const char*)(Bm + (size_t)(gcol0 + r) * KDIM + kt) + scb,
                  (char*)ldsB + it * 8192 + w * 1024);
        }
        __syncthreads();
#pragma unroll
        for (int kk = 0; kk < 64; kk += 32) {
            bf16x8 af[4], bfr[4];
            int cbyte = (kk + ((l >> 4) << 3)) * 2;
#pragma unroll
            for (int mi = 0; mi < 4; ++mi) {
                int rr = mbase + mi * 16 + (l & 15);
                af[mi] = *(const bf16x8*)((const char*)ldsA + ((rr * 128 + cbyte) ^ ((rr & 7) << 4)));
            }
#pragma unroll
            for (int ni = 0; ni < 4; ++ni) {
                int rr = nw * 32 + (ni & 1) * 16 + (ni >> 1) * 128 + (l & 15);
                bfr[ni] = *(const bf16x8*)((const char*)ldsB + ((rr * 128 + cbyte) ^ ((rr & 7) << 4)));
            }
#pragma unroll
            for (int mi = 0; mi < 4; ++mi)
#pragma unroll
                for (int ni = 0; ni < 4; ++ni)
                    acc[mi][ni] = __builtin_amdgcn_mfma_f32_16x16x32_bf16(af[mi], bfr[ni], acc[mi][ni], 0, 0, 0);
        }
    }
    // ---------------- fused epilogue (in-register) ----------------
    const float eps = 1.1920928955078125e-07f;
    if (ty < 2) {
#pragma unroll
        for (int mi = 0; mi < 4; ++mi)
#pragma unroll
            for (int r = 0; r < 4; ++r) {
                float ss = 0.f;
#pragma unroll
                for (int ni = 0; ni < 4; ++ni) { float v = acc[mi][ni][r]; ss += v * v; }
#pragma unroll
                for (int m = 1; m < 16; m <<= 1) ss += __shfl_xor(ss, m, 64);
                if ((l & 15) == 0) {
                    int rowl = mbase + mi * 16 + ((l >> 4) << 2) + r;
                    rowsum[rowl * 4 + nw] = ss;
                }
            }
        __syncthreads();
        const float tv = (ty == 0) ? tao[0] * 0.0625f : tao[1];
        u16* Obuf = (ty == 0) ? Qb : Kb;
#pragma unroll
        for (int mi = 0; mi < 4; ++mi)
#pragma unroll
            for (int r = 0; r < 4; ++r) {
                int rowl = mbase + mi * 16 + ((l >> 4) << 2) + r;
                int grow = row0 + rowl;
                if (grow >= MREAL) continue;
                int b = grow / TT, t = grow - b * TT;
                f32x4 rsv = *(const f32x4*)(rowsum + rowl * 4);
                float rs = rsv[0] + rsv[1] + rsv[2] + rsv[3];
                float scale = rsqrtf(rs * (1.0f / 256.0f) + eps) * tv;
                u16* dst = Obuf + ((size_t)((b * 8 + h) * TT + t) << 8);
#pragma unroll
                for (int nilo = 0; nilo < 2; ++nilo) {
                    int d = nw * 32 + nilo * 16 + (l & 15);
                    float c = cosb[t * 128 + d], s = sinb[t * 128 + d];
                    float xlo = acc[mi][nilo][r], xhi = acc[mi][nilo + 2][r];
                    dst[d]       = f2bf((xlo * c + xhi * s) * scale);
                    dst[d + 128] = f2bf((xhi * c - xlo * s) * scale);
                }
            }
    } else {
#pragma unroll
        for (int mi = 0; mi < 4; ++mi)
#pragma unroll
            for (int r = 0; r < 4; ++r) {
                int rowl = mbase + mi * 16 + ((l >> 4) << 2) + r;
                int grow = row0 + rowl;
                if (grow >= MREAL) continue;
                int b = grow / TT, t = grow - b * TT;
                int bh = b * 8 + h;
#pragma unroll
                for (int ni = 0; ni < 4; ++ni) {
                    int col = nw * 32 + (ni & 1) * 16 + (ni >> 1) * 128 + (l & 15);
                    u16 val = f2bf(acc[mi][ni][r]);
                    if (ty == 2) Vt[(size_t)(bh * 256 + col) * VTP + t] = val;
                    else         Gb[((size_t)(bh * TT + t) << 8) + col] = val;
                }
            }
    }
}

// ---------------- flash attention: KVBLK=32, 72KB LDS -> 2 blocks/CU ----------------
// Pair-cooperative waves (2j,2j+1): QK kv-halves of 16, PV d-halves of 128; P via LDS.
// Fixed-shift softmax; row sums via ones-operand MFMA; dbuf K/V with counted vmcnt.
// 64B-row tiles (V,P) use XOR swizzle ((row>>2)&3)<<4 (~2-way conflicts).
// 512 blocks = exactly 2/CU; cross-block wave overlap hides phase serialization (m114).
__global__ __launch_bounds__(512) void k_attn(const u16* __restrict__ Qb, const u16* __restrict__ Kb,
                                              const u16* __restrict__ Vt, const u16* __restrict__ Gb,
                                              const float* __restrict__ tao,
                                              u16* __restrict__ Y) {
    __shared__ __align__(16) u16 Kt[2][32 * 256];   // 16KB each
    __shared__ __align__(16) u16 Vl[2][256 * 32];   // 16KB each
    __shared__ __align__(16) u16 Plds[8][16 * 32];  // 8KB; total 72KB
    const int tid = threadIdx.x, l = tid & 63, w = tid >> 6;
    const int qt = 15 - (blockIdx.x >> 5);          // heavy tiles first
    const int bh = blockIdx.x & 31;                 // pinned to XCD bh%8
    const int b = bh >> 3, h = bh & 7;
    const int g0 = (w >> 1) * 2;                    // this pair's first group
    const int kvh = (w & 1) * 16;                   // QK kv-half offset (16 rows)
    const int dh = (w & 1) * 128;                   // PV d-half offset
    const int mq_g0 = qt * 128 + g0 * 16 + 1;       // first q-row of the pair
    const size_t qkbase = (size_t)bh * TT * 256;
    const size_t vrow0 = (size_t)bh * 256;
    const float Cs = tao[0] * tao[1] * 16.0f;       // score upper bound (rmsnorm)

    bf16x8 aq[2][8];
#pragma unroll
    for (int g = 0; g < 2; ++g) {
        int mq = mq_g0 + g * 16 + (l & 15);
        const u16* qp = Qb + qkbase + ((size_t)mq << 8) + ((l >> 4) << 3);
#pragma unroll
        for (int kk = 0; kk < 8; ++kk) aq[g][kk] = *(const bf16x8*)(qp + kk * 32);
    }
    bf16x8 vone;
#pragma unroll
    for (int i = 0; i < 8; ++i) vone[i] = (short)0x3F80;
    f32x4 acc[2][8], accs[2];
    const f32x4 zero = {0.f, 0.f, 0.f, 0.f};
#pragma unroll
    for (int g = 0; g < 2; ++g) {
#pragma unroll
        for (int i = 0; i < 8; ++i) acc[g][i] = zero;
        accs[g] = zero;
    }

    const int nkv = 4 * qt + 5;

    auto STAGE = [&](int j, int bufi) {
        const int kv0 = j << 5;
#pragma unroll
        for (int it = 0; it < 2; ++it) {    // K: 32 rows x 512B
            int lin = (it * 512 + tid) * 16;
            int r = lin >> 9, cbyt = lin & 511;
            int scb = cbyt ^ ((r & 7) << 4);
            int krow = kv0 + r; if (krow > 2048) krow = 2048;
            GLD16((const char*)(Kb + qkbase + ((size_t)krow << 8)) + scb,
                  (char*)&Kt[bufi][0] + it * 8192 + w * 1024);
        }
#pragma unroll
        for (int it = 0; it < 2; ++it) {    // V^T: 256 rows x 64B
            int lin = (it * 512 + tid) * 16;
            int vr = lin >> 6, cb = lin & 63;
            int scv = cb ^ (((vr >> 2) & 3) << 4);
            GLD16((const char*)(Vt + (vrow0 + vr) * VTP + kv0) + scv,
                  (char*)&Vl[bufi][0] + it * 8192 + w * 1024);
        }
    };

    STAGE(0, 0);
    int buf = 0;

    for (int j = 0; j < nkv; ++j) {
        const int kv0 = j << 5;
        if (j + 1 < nkv) { STAGE(j + 1, buf ^ 1); VMCNT(4); }
        else             { VMCNT(0); }
        SBAR(); MEMFENCE();

        const bool active = (kv0 <= mq_g0 + 31);
        if (active) {
            // ---- QK^T: both groups, this wave's 16-row kv-half ----
            f32x4 s[2] = {zero, zero};
            __builtin_amdgcn_s_setprio(1);
#pragma unroll
            for (int kk = 0; kk < 8; ++kk) {
                int cbyte = kk * 64 + ((l >> 4) << 4);
                int rr = kvh + (l & 15);
                bf16x8 bk = *(const bf16x8*)((const char*)&Kt[buf][0] + ((rr * 512 + cbyte) ^ ((rr & 7) << 4)));
#pragma unroll
                for (int g = 0; g < 2; ++g)
                    s[g] = __builtin_amdgcn_mfma_f32_16x16x32_bf16(aq[g][kk], bk, s[g], 0, 0, 0);
            }
            __builtin_amdgcn_s_setprio(0);
            // ---- mask + exp + P write ----
#pragma unroll
            for (int g = 0; g < 2; ++g) {
                char* pwb = (char*)&Plds[g0 + g][0];
                const bool needmask = (kv0 + kvh + 15 > mq_g0 + g * 16);
#pragma unroll
                for (int r = 0; r < 4; ++r) {
                    float sv = s[g][r];
                    if (needmask) {
                        int kg = kv0 + kvh + (l & 15);
                        int qg = mq_g0 + g * 16 + ((l >> 4) << 2) + r;
                        if (kg > qg) sv = -1e30f;
                    }
                    float pv = __expf(sv - Cs);
                    int row = ((l >> 4) << 2) + r;
                    int byte = row * 64 + (kvh + (l & 15)) * 2;
                    *(u16*)(pwb + (byte ^ (((row >> 2) & 3) << 4))) = f2bf(pv);
                }
            }
        }
        LGKMCNT0(); SBAR(); MEMFENCE();       // P exchange within pair

        if (active) {
            // ---- PV: both groups, this wave's d-half ----
            bf16x8 ap[2];
#pragma unroll
            for (int g = 0; g < 2; ++g) {
                const char* prb = (const char*)&Plds[g0 + g][0];
                int row = l & 15;
                int b0 = row * 64 + ((l >> 4) << 4);
                ap[g] = *(const bf16x8*)(prb + (b0 ^ (((row >> 2) & 3) << 4)));
            }
            __builtin_amdgcn_s_setprio(1);
#pragma unroll
            for (int df = 0; df < 8; ++df) {
                int vr = dh + df * 16 + (l & 15);
                int cb2 = vr * 64 + ((l >> 4) << 4);
                bf16x8 bv = *(const bf16x8*)((const char*)&Vl[buf][0] + (cb2 ^ (((vr >> 2) & 3) << 4)));
#pragma unroll
                for (int g = 0; g < 2; ++g)
                    acc[g][df] = __builtin_amdgcn_mfma_f32_16x16x32_bf16(ap[g], bv, acc[g][df], 0, 0, 0);
            }
#pragma unroll
            for (int g = 0; g < 2; ++g)
                accs[g] = __builtin_amdgcn_mfma_f32_16x16x32_bf16(ap[g], vone, accs[g], 0, 0, 0);
            __builtin_amdgcn_s_setprio(0);
        }
        MEMFENCE(); SBAR();
        buf ^= 1;
    }
    // ---- epilogue: both groups, this wave's d-half ----
#pragma unroll
    for (int g = 0; g < 2; ++g)
#pragma unroll
        for (int r = 0; r < 4; ++r) {
            int mq = mq_g0 + g * 16 + ((l >> 4) << 2) + r;   // 1..2048 always
            float inv = 1.0f / accs[g][r];
            const u16* gp = Gb + qkbase + ((size_t)mq << 8) + dh + (l & 15);
            u16* yp = Y + ((size_t)(b * 2048 + mq - 1)) * 2048 + h * 256 + dh + (l & 15);
#pragma unroll
            for (int df = 0; df < 8; ++df) {
                float g2 = bf2f(gp[df * 16]);
                float sg = 1.0f / (1.0f + __expf(-g2));
                yp[df * 16] = f2bf(acc[g][df][r] * inv * sg);
            }
        }
}

// ---------------- GEMM3: out = Y @ Wout^T (round-11 form: BM=64, BN=64, 512 blocks) --
__global__ __launch_bounds__(256) void k_gemm_out(const u16* __restrict__ A, const u16* __restrict__ Bm,
                                                  float* __restrict__ Cout) {
    __shared__ __align__(16) u16 ldsA[64 * 64];
    __shared__ __align__(16) u16 ldsB[64 * 64];
    const int tid = threadIdx.x;
    const int l = tid & 63, w = tid >> 6;
    const int row0 = blockIdx.x * 64, col0 = blockIdx.y * 64;
    const int mbase = (w >> 1) * 32, nbase = (w & 1) * 32;
    const int K2 = 2048;
    f32x4 acc[2][2];
    const f32x4 zero = {0.f, 0.f, 0.f, 0.f};
#pragma unroll
    for (int i = 0; i < 2; ++i)
#pragma unroll
        for (int j = 0; j < 2; ++j) acc[i][j] = zero;

    for (int kt = 0; kt < K2; kt += 64) {
        __syncthreads();
#pragma unroll
        for (int it = 0; it < 2; ++it) {
            int lin = (it * 256 + tid) * 16;
            int r = lin >> 7;
            int cb = lin & 127;
            int scb = cb ^ ((r & 7) << 4);
            GLD16((const char*)(A + (size_t)(row0 + r) * K2 + kt) + scb,
                  (char*)ldsA + it * 4096 + w * 1024);
            GLD16((const char*)(Bm + (size_t)(col0 + r) * K2 + kt) + scb,
                  (char*)ldsB + it * 4096 + w * 1024);
        }
        __syncthreads();
#pragma unroll
        for (int kk = 0; kk < 64; kk += 32) {
            bf16x8 af[2], bfr[2];
            int cbyte = (kk + ((l >> 4) << 3)) * 2;
#pragma unroll
            for (int mi = 0; mi < 2; ++mi) {
                int rr = mbase + mi * 16 + (l & 15);
                af[mi] = *(const bf16x8*)((const char*)ldsA + ((rr * 128 + cbyte) ^ ((rr & 7) << 4)));
            }
#pragma unroll
            for (int ni = 0; ni < 2; ++ni) {
                int rr = nbase + ni * 16 + (l & 15);
                bfr[ni] = *(const bf16x8*)((const char*)ldsB + ((rr * 128 + cbyte) ^ ((rr & 7) << 4)));
            }
#pragma unroll
            for (int mi = 0; mi < 2; ++mi)
#pragma unroll
                for (int ni = 0; ni < 2; ++ni)
                    acc[mi][ni] = __builtin_amdgcn_mfma_f32_16x16x32_bf16(af[mi], bfr[ni], acc[mi][ni], 0, 0, 0);
        }
    }
#pragma unroll
    for (int mi = 0; mi < 2; ++mi)
#pragma unroll
        for (int ni = 0; ni < 2; ++ni)
#pragma unroll
            for (int r = 0; r < 4; ++r) {
                int grow = row0 + mbase + mi * 16 + ((l >> 4) << 2) + r;
                int gcol = col0 + nbase + ni * 16 + (l & 15);
                Cout[(size_t)grow * 256 + gcol] = acc[mi][ni][r];
            }
}

extern "C" void kernel_launch(void* const* d_in, const int* in_sizes, int n_in,
                              void* d_out, int out_size, void* d_ws, size_t ws_size,
                              hipStream_t stream) {
    const float* x     = (const float*)d_in[0];
    const float* cosb  = (const float*)d_in[1];
    const float* sinb  = (const float*)d_in[2];
    const float* wqkvg = (const float*)d_in[3];
    const float* wsink = (const float*)d_in[4];
    const float* wout  = (const float*)d_in[5];
    const float* tao   = (const float*)d_in[6];
    float* out = (float*)d_out;

    char* ws = (char*)d_ws;
    u16* x0b = (u16*)(ws + 0);            // 8320*256*2       = 4,259,840
    u16* wqb = (u16*)(ws + 4259840);      // 8192*256*2       = 4,194,304
    u16* wob = (u16*)(ws + 8454144);      // 256*2048*2       = 1,048,576
    u16* Qb  = (u16*)(ws + 9502720);      // 32*2049*256*2    = 33,570,816
    u16* Kb  = (u16*)(ws + 43073536);     // 33,570,816
    u16* Gb  = (u16*)(ws + 76644352);     // 33,570,816
    u16* Vt  = (u16*)(ws + 110215168);    // 32*256*2112*2    = 34,603,008
    u16* Yb  = (u16*)(ws + 144818176);    // 8192*2048*2      = 33,554,432
    // total 178,372,608 bytes

    k_conv_x0<<<dim3((MPAD * 64 + 255) / 256), 256, 0, stream>>>(x, wsink, x0b);
    k_conv_bf16<<<dim3((NQ * 64 + 255) / 256), 256, 0, stream>>>(wqkvg, wqb, NQ * 64);
    k_conv_bf16<<<dim3((256 * 512 + 255) / 256), 256, 0, stream>>>(wout, wob, 256 * 512);
    k_gemm_qkvg<<<dim3(65, 32), 512, 0, stream>>>(x0b, wqb, cosb, sinb, tao, Qb, Kb, Vt, Gb);
    k_attn<<<dim3(16 * 32), 512, 0, stream>>>(Qb, Kb, Vt, Gb, tao, Yb);
    k_gemm_out<<<dim3(128, 4), 256, 0, stream>>>(Yb, wob, out);
}

// Round 13
// 266.375 us; speedup vs baseline: 1.0873x; 1.0873x over previous
//
#include <hip/hip_runtime.h>
#include <stdint.h>

#define DEVI __device__ __forceinline__

typedef __attribute__((ext_vector_type(8))) short bf16x8;
typedef __attribute__((ext_vector_type(4))) float f32x4;
typedef unsigned short u16;
typedef unsigned int u32;

#define TT 2049           // T+1
#define BH 32             // B*H
#define MPAD 8320         // 65*128
#define MREAL 8196        // 4*2049
#define NQ 8192           // 4*N_QKV
#define KDIM 256
#define VTP 2112          // padded t-stride for V^T

#define SBAR() __builtin_amdgcn_s_barrier()
#define MEMFENCE() asm volatile("" ::: "memory")
#define VMCNT(n) asm volatile("s_waitcnt vmcnt(" #n ")" ::: "memory")
#define LGKMCNT0() asm volatile("s_waitcnt lgkmcnt(0)" ::: "memory")

DEVI u16 f2bf(float f) {
    union { float f; u32 u; } v; v.f = f;
    u32 r = v.u + 0x7FFF + ((v.u >> 16) & 1);
    return (u16)(r >> 16);
}
DEVI float bf2f(u16 h) {
    union { u32 u; float f; } v; v.u = ((u32)h) << 16;
    return v.f;
}

#define GLD16(src, lds) __builtin_amdgcn_global_load_lds( \
    (const __attribute__((address_space(1))) void*)(src), \
    (__attribute__((address_space(3))) void*)(lds), 16, 0, 0)

// ---------------- single merged conversion kernel (x4 vectorized) ----------------
#define CN0 (MPAD * 64)         // x0b units
#define CN1 (NQ * 64)           // wqb units
#define CN2 (256 * 512)         // wob units
__global__ void k_conv_all(const float* __restrict__ x, const float* __restrict__ wsink,
                           const float* __restrict__ wqkvg, const float* __restrict__ wout,
                           u16* __restrict__ x0b, u16* __restrict__ wqb, u16* __restrict__ wob) {
    int idx = blockIdx.x * 256 + threadIdx.x;
    const float* src = nullptr;
    u16* dst = nullptr;
    int oidx = idx;
    bool zero_fill = false;
    if (idx < CN0) {
        int m = idx >> 6, c = (idx & 63) << 2;
        if (m < MREAL) {
            int b = m / TT, t = m - b * TT;
            src = (t == 0) ? (wsink + c) : (x + ((size_t)((b << 11) + t - 1) << 8) + c);
        } else zero_fill = true;
        dst = x0b;
    } else if (idx < CN0 + CN1) {
        oidx = idx - CN0;
        src = wqkvg + ((size_t)oidx << 2);
        dst = wqb;
    } else if (idx < CN0 + CN1 + CN2) {
        oidx = idx - CN0 - CN1;
        src = wout + ((size_t)oidx << 2);
        dst = wob;
    } else return;
    f32x4 v = {0.f, 0.f, 0.f, 0.f};
    if (!zero_fill) v = *(const f32x4*)src;
    union { u16 h[4]; uint2 u2; } o;
#pragma unroll
    for (int i = 0; i < 4; ++i) o.h[i] = f2bf(v[i]);
    *(uint2*)(dst + ((size_t)oidx << 2)) = o.u2;
}

// ---------------- GEMM1: qkvg = x0 @ Wqkvg^T with in-register rope+rms epilogue ------
// (round-10 form, unchanged)
__global__ __launch_bounds__(512) void k_gemm_qkvg(const u16* __restrict__ A, const u16* __restrict__ Bm,
                                                   const float* __restrict__ cosb, const float* __restrict__ sinb,
                                                   const float* __restrict__ tao,
                                                   u16* __restrict__ Qb, u16* __restrict__ Kb,
                                                   u16* __restrict__ Vt, u16* __restrict__ Gb) {
    __shared__ __align__(16) u16 ldsA[128 * 64];      // 16KB
    __shared__ __align__(16) u16 ldsB[256 * 64];      // 32KB
    __shared__ float rowsum[128 * 4];                 // 2KB
    const int tid = threadIdx.x, l = tid & 63, w = tid >> 6;
    const int row0 = blockIdx.x * 128;
    const int gcol0 = blockIdx.y * 256;
    const int h = gcol0 >> 10, ty = (gcol0 & 1023) >> 8;
    const int mbase = (w >> 2) * 64, nw = w & 3;
    f32x4 acc[4][4];
    const f32x4 zero = {0.f, 0.f, 0.f, 0.f};
#pragma unroll
    for (int i = 0; i < 4; ++i)
#pragma unroll
        for (int j = 0; j < 4; ++j) acc[i][j] = zero;

    for (int kt = 0; kt < KDIM; kt += 64) {
        __syncthreads();
#pragma unroll
        for (int it = 0; it < 2; ++it) {      // A: 128 rows of 128B
            int lin = (it * 512 + tid) * 16;
            int r = lin >> 7, cb = lin & 127;
            int scb = cb ^ ((r & 7) << 4);
            GLD16((const char*)(A + (size_t)(row0 + r) * KDIM + kt) + scb,
                  (char*)ldsA + it * 8192 + w * 1024);
        }
#pragma unroll
        for (int it = 0; it < 4; ++it) {      // B: 256 rows of 128B
            int lin = (it * 512 + tid) * 16;
            int r = lin >> 7, cb = lin & 127;
            int scb = cb ^ ((r & 7) << 4);
            GLD16((const char*)(Bm + (size_t)(gcol0 + r) * KDIM + kt) + scb,
                  (char*)ldsB + it * 8192 + w * 1024);
        }
        __syncthreads();
#pragma unroll
        for (int kk = 0; kk < 64; kk += 32) {
            bf16x8 af[4], bfr[4];
            int cbyte = (kk + ((l >> 4) << 3)) * 2;
#pragma unroll
            for (int mi = 0; mi < 4; ++mi) {
                int rr = mbase + mi * 16 + (l & 15);
                af[mi] = *(const bf16x8*)((const char*)ldsA + ((rr * 128 + cbyte) ^ ((rr & 7) << 4)));
            }
#pragma unroll
            for (int ni = 0; ni < 4; ++ni) {
                int rr = nw * 32 + (ni & 1) * 16 + (ni >> 1) * 128 + (l & 15);
                bfr[ni] = *(const bf16x8*)((const char*)ldsB + ((rr * 128 + cbyte) ^ ((rr & 7) << 4)));
            }
#pragma unroll
            for (int mi = 0; mi < 4; ++mi)
#pragma unroll
                for (int ni = 0; ni < 4; ++ni)
                    acc[mi][ni] = __builtin_amdgcn_mfma_f32_16x16x32_bf16(af[mi], bfr[ni], acc[mi][ni], 0, 0, 0);
        }
    }
    // ---------------- fused epilogue (in-register) ----------------
    const float eps = 1.1920928955078125e-07f;
    if (ty < 2) {
#pragma unroll
        for (int mi = 0; mi < 4; ++mi)
#pragma unroll
            for (int r = 0; r < 4; ++r) {
                float ss = 0.f;
#pragma unroll
                for (int ni = 0; ni < 4; ++ni) { float v = acc[mi][ni][r]; ss += v * v; }
#pragma unroll
                for (int m = 1; m < 16; m <<= 1) ss += __shfl_xor(ss, m, 64);
                if ((l & 15) == 0) {
                    int rowl = mbase + mi * 16 + ((l >> 4) << 2) + r;
                    rowsum[rowl * 4 + nw] = ss;
                }
            }
        __syncthreads();
        const float tv = (ty == 0) ? tao[0] * 0.0625f : tao[1];
        u16* Obuf = (ty == 0) ? Qb : Kb;
#pragma unroll
        for (int mi = 0; mi < 4; ++mi)
#pragma unroll
            for (int r = 0; r < 4; ++r) {
                int rowl = mbase + mi * 16 + ((l >> 4) << 2) + r;
                int grow = row0 + rowl;
                if (grow >= MREAL) continue;
                int b = grow / TT, t = grow - b * TT;
                f32x4 rsv = *(const f32x4*)(rowsum + rowl * 4);
                float rs = rsv[0] + rsv[1] + rsv[2] + rsv[3];
                float scale = rsqrtf(rs * (1.0f / 256.0f) + eps) * tv;
                u16* dst = Obuf + ((size_t)((b * 8 + h) * TT + t) << 8);
#pragma unroll
                for (int nilo = 0; nilo < 2; ++nilo) {
                    int d = nw * 32 + nilo * 16 + (l & 15);
                    float c = cosb[t * 128 + d], s = sinb[t * 128 + d];
                    float xlo = acc[mi][nilo][r], xhi = acc[mi][nilo + 2][r];
                    dst[d]       = f2bf((xlo * c + xhi * s) * scale);
                    dst[d + 128] = f2bf((xhi * c - xlo * s) * scale);
                }
            }
    } else {
#pragma unroll
        for (int mi = 0; mi < 4; ++mi)
#pragma unroll
            for (int r = 0; r < 4; ++r) {
                int rowl = mbase + mi * 16 + ((l >> 4) << 2) + r;
                int grow = row0 + rowl;
                if (grow >= MREAL) continue;
                int b = grow / TT, t = grow - b * TT;
                int bh = b * 8 + h;
#pragma unroll
                for (int ni = 0; ni < 4; ++ni) {
                    int col = nw * 32 + (ni & 1) * 16 + (ni >> 1) * 128 + (l & 15);
                    u16 val = f2bf(acc[mi][ni][r]);
                    if (ty == 2) Vt[(size_t)(bh * 256 + col) * VTP + t] = val;
                    else         Gb[((size_t)(bh * TT + t) << 8) + col] = val;
                }
            }
    }
}

// ---------------- flash attention (round-11 form: KVBLK=64 pair-cooperative) --------
__global__ __launch_bounds__(512) void k_attn(const u16* __restrict__ Qb, const u16* __restrict__ Kb,
                                              const u16* __restrict__ Vt, const u16* __restrict__ Gb,
                                              const float* __restrict__ tao,
                                              u16* __restrict__ Y) {
    __shared__ __align__(16) u16 Kt[2][64 * 256];   // 32KB each
    __shared__ __align__(16) u16 Vl[2][256 * 64];   // 32KB each
    __shared__ __align__(16) u16 Plds[8][16 * 64];  // per-GROUP P tile, swizzled; 16KB
    const int tid = threadIdx.x, l = tid & 63, w = tid >> 6;
    const int qt = 15 - (blockIdx.x >> 5);          // heavy tiles first
    const int bh = blockIdx.x & 31;                 // pinned to XCD bh%8
    const int b = bh >> 3, h = bh & 7;
    const int g0 = (w >> 1) * 2;                    // this pair's first group
    const int kvh = (w & 1) * 32;                   // QK kv-half offset
    const int dh = (w & 1) * 128;                   // PV d-half offset
    const int mq_g0 = qt * 128 + g0 * 16 + 1;       // first q-row of the pair
    const size_t qkbase = (size_t)bh * TT * 256;
    const size_t vrow0 = (size_t)bh * 256;
    const float Cs = tao[0] * tao[1] * 16.0f;       // score upper bound (rmsnorm)

    bf16x8 aq[2][8];
#pragma unroll
    for (int g = 0; g < 2; ++g) {
        int mq = mq_g0 + g * 16 + (l & 15);
        const u16* qp = Qb + qkbase + ((size_t)mq << 8) + ((l >> 4) << 3);
#pragma unroll
        for (int kk = 0; kk < 8; ++kk) aq[g][kk] = *(const bf16x8*)(qp + kk * 32);
    }
    bf16x8 vone;
#pragma unroll
    for (int i = 0; i < 8; ++i) vone[i] = (short)0x3F80;
    f32x4 acc[2][8], accs[2];
    const f32x4 zero = {0.f, 0.f, 0.f, 0.f};
#pragma unroll
    for (int g = 0; g < 2; ++g) {
#pragma unroll
        for (int i = 0; i < 8; ++i) acc[g][i] = zero;
        accs[g] = zero;
    }

    const int nkv = 2 * qt + 3;

    auto STAGE = [&](int j, int bufi) {
        const int kv0 = j << 6;
#pragma unroll
        for (int it = 0; it < 4; ++it) {
            int lin = (it * 512 + tid) * 16;
            {
                int r = lin >> 9, cbyt = lin & 511;
                int scb = cbyt ^ ((r & 7) << 4);
                int krow = kv0 + r; if (krow > 2048) krow = 2048;
                GLD16((const char*)(Kb + qkbase + ((size_t)krow << 8)) + scb,
                      (char*)&Kt[bufi][0] + it * 8192 + w * 1024);
            }
            {
                int vr = lin >> 7, cb = lin & 127;
                int scb = cb ^ ((vr & 7) << 4);
                GLD16((const char*)(Vt + (vrow0 + vr) * VTP + kv0) + scb,
                      (char*)&Vl[bufi][0] + it * 8192 + w * 1024);
            }
        }
    };

    STAGE(0, 0);
    int buf = 0;

    for (int j = 0; j < nkv; ++j) {
        const int kv0 = j << 6;
        if (j + 1 < nkv) { STAGE(j + 1, buf ^ 1); VMCNT(8); }
        else             { VMCNT(0); }
        SBAR(); MEMFENCE();

        const bool active = (kv0 <= mq_g0 + 31);
        if (active) {
            f32x4 s[2][2];
#pragma unroll
            for (int g = 0; g < 2; ++g) { s[g][0] = zero; s[g][1] = zero; }
            __builtin_amdgcn_s_setprio(1);
#pragma unroll
            for (int kk = 0; kk < 8; ++kk) {
                int cbyte = kk * 64 + ((l >> 4) << 4);
#pragma unroll
                for (int t = 0; t < 2; ++t) {
                    int rr = kvh + t * 16 + (l & 15);
                    bf16x8 bk = *(const bf16x8*)((const char*)&Kt[buf][0] + ((rr * 512 + cbyte) ^ ((rr & 7) << 4)));
#pragma unroll
                    for (int g = 0; g < 2; ++g)
                        s[g][t] = __builtin_amdgcn_mfma_f32_16x16x32_bf16(aq[g][kk], bk, s[g][t], 0, 0, 0);
                }
            }
            __builtin_amdgcn_s_setprio(0);
#pragma unroll
            for (int g = 0; g < 2; ++g) {
                char* pwb = (char*)&Plds[g0 + g][0];
                const bool needmask = (kv0 + kvh + 31 > mq_g0 + g * 16);
#pragma unroll
                for (int t = 0; t < 2; ++t)
#pragma unroll
                    for (int r = 0; r < 4; ++r) {
                        float sv = s[g][t][r];
                        if (needmask) {
                            int kg = kv0 + kvh + t * 16 + (l & 15);
                            int qg = mq_g0 + g * 16 + ((l >> 4) << 2) + r;
                            if (kg > qg) sv = -1e30f;
                        }
                        float pv = __expf(sv - Cs);
                        int row = ((l >> 4) << 2) + r;
                        int byte = row * 128 + (kvh + t * 16 + (l & 15)) * 2;
                        *(u16*)(pwb + (byte ^ ((row & 7) << 4))) = f2bf(pv);
                    }
            }
        }
        LGKMCNT0(); SBAR(); MEMFENCE();

        if (active) {
            bf16x8 ap[2][2];
#pragma unroll
            for (int g = 0; g < 2; ++g) {
                const char* prb = (const char*)&Plds[g0 + g][0];
                int row = l & 15;
                int b0 = row * 128 + ((l >> 4) << 4);
                ap[g][0] = *(const bf16x8*)(prb + (b0 ^ ((row & 7) << 4)));
                ap[g][1] = *(const bf16x8*)(prb + ((b0 + 64) ^ ((row & 7) << 4)));
            }
            __builtin_amdgcn_s_setprio(1);
#pragma unroll
            for (int df = 0; df < 8; ++df) {
                int vr = dh + df * 16 + (l & 15);
                int cbase = vr * 128 + ((l >> 4) << 4);
                bf16x8 bv0 = *(const bf16x8*)((const char*)&Vl[buf][0] + (cbase ^ ((vr & 7) << 4)));
                bf16x8 bv1 = *(const bf16x8*)((const char*)&Vl[buf][0] + ((cbase + 64) ^ ((vr & 7) << 4)));
#pragma unroll
                for (int g = 0; g < 2; ++g) {
                    acc[g][df] = __builtin_amdgcn_mfma_f32_16x16x32_bf16(ap[g][0], bv0, acc[g][df], 0, 0, 0);
                    acc[g][df] = __builtin_amdgcn_mfma_f32_16x16x32_bf16(ap[g][1], bv1, acc[g][df], 0, 0, 0);
                }
            }
#pragma unroll
            for (int g = 0; g < 2; ++g) {
                accs[g] = __builtin_amdgcn_mfma_f32_16x16x32_bf16(ap[g][0], vone, accs[g], 0, 0, 0);
                accs[g] = __builtin_amdgcn_mfma_f32_16x16x32_bf16(ap[g][1], vone, accs[g], 0, 0, 0);
            }
            __builtin_amdgcn_s_setprio(0);
        }
        MEMFENCE(); SBAR();
        buf ^= 1;
    }
#pragma unroll
    for (int g = 0; g < 2; ++g)
#pragma unroll
        for (int r = 0; r < 4; ++r) {
            int mq = mq_g0 + g * 16 + ((l >> 4) << 2) + r;
            float inv = 1.0f / accs[g][r];
            const u16* gp = Gb + qkbase + ((size_t)mq << 8) + dh + (l & 15);
            u16* yp = Y + ((size_t)(b * 2048 + mq - 1)) * 2048 + h * 256 + dh + (l & 15);
#pragma unroll
            for (int df = 0; df < 8; ++df) {
                float g2 = bf2f(gp[df * 16]);
                float sg = 1.0f / (1.0f + __expf(-g2));
                yp[df * 16] = f2bf(acc[g][df][r] * inv * sg);
            }
        }
}

// ---------------- GEMM3: out = Y @ Wout^T (round-11 form: BM=64, BN=64, 512 blocks) --
__global__ __launch_bounds__(256) void k_gemm_out(const u16* __restrict__ A, const u16* __restrict__ Bm,
                                                  float* __restrict__ Cout) {
    __shared__ __align__(16) u16 ldsA[64 * 64];
    __shared__ __align__(16) u16 ldsB[64 * 64];
    const int tid = threadIdx.x;
    const int l = tid & 63, w = tid >> 6;
    const int row0 = blockIdx.x * 64, col0 = blockIdx.y * 64;
    const int mbase = (w >> 1) * 32, nbase = (w & 1) * 32;
    const int K2 = 2048;
    f32x4 acc[2][2];
    const f32x4 zero = {0.f, 0.f, 0.f, 0.f};
#pragma unroll
    for (int i = 0; i < 2; ++i)
#pragma unroll
        for (int j = 0; j < 2; ++j) acc[i][j] = zero;

    for (int kt = 0; kt < K2; kt += 64) {
        __syncthreads();
#pragma unroll
        for (int it = 0; it < 2; ++it) {
            int lin = (it * 256 + tid) * 16;
            int r = lin >> 7;
            int cb = lin & 127;
            int scb = cb ^ ((r & 7) << 4);
            GLD16((const char*)(A + (size_t)(row0 + r) * K2 + kt) + scb,
                  (char*)ldsA + it * 4096 + w * 1024);
            GLD16((const char*)(Bm + (size_t)(col0 + r) * K2 + kt) + scb,
                  (char*)ldsB + it * 4096 + w * 1024);
        }
        __syncthreads();
#pragma unroll
        for (int kk = 0; kk < 64; kk += 32) {
            bf16x8 af[2], bfr[2];
            int cbyte = (kk + ((l >> 4) << 3)) * 2;
#pragma unroll
            for (int mi = 0; mi < 2; ++mi) {
                int rr = mbase + mi * 16 + (l & 15);
                af[mi] = *(const bf16x8*)((const char*)ldsA + ((rr * 128 + cbyte) ^ ((rr & 7) << 4)));
            }
#pragma unroll
            for (int ni = 0; ni < 2; ++ni) {
                int rr = nbase + ni * 16 + (l & 15);
                bfr[ni] = *(const bf16x8*)((const char*)ldsB + ((rr * 128 + cbyte) ^ ((rr & 7) << 4)));
            }
#pragma unroll
            for (int mi = 0; mi < 2; ++mi)
#pragma unroll
                for (int ni = 0; ni < 2; ++ni)
                    acc[mi][ni] = __builtin_amdgcn_mfma_f32_16x16x32_bf16(af[mi], bfr[ni], acc[mi][ni], 0, 0, 0);
        }
    }
#pragma unroll
    for (int mi = 0; mi < 2; ++mi)
#pragma unroll
        for (int ni = 0; ni < 2; ++ni)
#pragma unroll
            for (int r = 0; r < 4; ++r) {
                int grow = row0 + mbase + mi * 16 + ((l >> 4) << 2) + r;
                int gcol = col0 + nbase + ni * 16 + (l & 15);
                Cout[(size_t)grow * 256 + gcol] = acc[mi][ni][r];
            }
}

extern "C" void kernel_launch(void* const* d_in, const int* in_sizes, int n_in,
                              void* d_out, int out_size, void* d_ws, size_t ws_size,
                              hipStream_t stream) {
    const float* x     = (const float*)d_in[0];
    const float* cosb  = (const float*)d_in[1];
    const float* sinb  = (const float*)d_in[2];
    const float* wqkvg = (const float*)d_in[3];
    const float* wsink = (const float*)d_in[4];
    const float* wout  = (const float*)d_in[5];
    const float* tao   = (const float*)d_in[6];
    float* out = (float*)d_out;

    char* ws = (char*)d_ws;
    u16* x0b = (u16*)(ws + 0);            // 8320*256*2       = 4,259,840
    u16* wqb = (u16*)(ws + 4259840);      // 8192*256*2       = 4,194,304
    u16* wob = (u16*)(ws + 8454144);      // 256*2048*2       = 1,048,576
    u16* Qb  = (u16*)(ws + 9502720);      // 32*2049*256*2    = 33,570,816
    u16* Kb  = (u16*)(ws + 43073536);     // 33,570,816
    u16* Gb  = (u16*)(ws + 76644352);     // 33,570,816
    u16* Vt  = (u16*)(ws + 110215168);    // 32*256*2112*2    = 34,603,008
    u16* Yb  = (u16*)(ws + 144818176);    // 8192*2048*2      = 33,554,432
    // total 178,372,608 bytes

    k_conv_all<<<dim3((CN0 + CN1 + CN2 + 255) / 256), 256, 0, stream>>>(
        x, wsink, wqkvg, wout, x0b, wqb, wob);
    k_gemm_qkvg<<<dim3(65, 32), 512, 0, stream>>>(x0b, wqb, cosb, sinb, tao, Qb, Kb, Vt, Gb);
    k_attn<<<dim3(16 * 32), 512, 0, stream>>>(Qb, Kb, Vt, Gb, tao, Yb);
    k_gemm_out<<<dim3(128, 4), 256, 0, stream>>>(Yb, wob, out);
}

// Round 14
// 226.794 us; speedup vs baseline: 1.2770x; 1.1745x over previous
//
#include <hip/hip_runtime.h>
#include <stdint.h>

#define DEVI __device__ __forceinline__

typedef __attribute__((ext_vector_type(8))) short bf16x8;
typedef __attribute__((ext_vector_type(4))) float f32x4;
typedef __attribute__((ext_vector_type(4))) unsigned short u16x4;
typedef unsigned short u16;
typedef unsigned int u32;

#define TT 2049           // T+1
#define BH 32             // B*H
#define MPAD 8320         // 65*128
#define MREAL 8196        // 4*2049
#define NQ 8192           // 4*N_QKV
#define KDIM 256
#define VTP 2112          // padded t-stride for V^T

#define SBAR() __builtin_amdgcn_s_barrier()
#define MEMFENCE() asm volatile("" ::: "memory")
#define VMCNT(n) asm volatile("s_waitcnt vmcnt(" #n ")" ::: "memory")
#define LGKMCNT0() asm volatile("s_waitcnt lgkmcnt(0)" ::: "memory")

DEVI u16 f2bf(float f) {
    union { float f; u32 u; } v; v.f = f;
    u32 r = v.u + 0x7FFF + ((v.u >> 16) & 1);
    return (u16)(r >> 16);
}
DEVI float bf2f(u16 h) {
    union { u32 u; float f; } v; v.u = ((u32)h) << 16;
    return v.f;
}

#define GLD16(src, lds) __builtin_amdgcn_global_load_lds( \
    (const __attribute__((address_space(1))) void*)(src), \
    (__attribute__((address_space(3))) void*)(lds), 16, 0, 0)

// ---------------- single merged conversion kernel (x4 vectorized) ----------------
#define CN0 (MPAD * 64)         // x0b units
#define CN1 (NQ * 64)           // wqb units
#define CN2 (256 * 512)         // wob units
__global__ void k_conv_all(const float* __restrict__ x, const float* __restrict__ wsink,
                           const float* __restrict__ wqkvg, const float* __restrict__ wout,
                           u16* __restrict__ x0b, u16* __restrict__ wqb, u16* __restrict__ wob) {
    int idx = blockIdx.x * 256 + threadIdx.x;
    const float* src = nullptr;
    u16* dst = nullptr;
    int oidx = idx;
    bool zero_fill = false;
    if (idx < CN0) {
        int m = idx >> 6, c = (idx & 63) << 2;
        if (m < MREAL) {
            int b = m / TT, t = m - b * TT;
            src = (t == 0) ? (wsink + c) : (x + ((size_t)((b << 11) + t - 1) << 8) + c);
        } else zero_fill = true;
        dst = x0b;
    } else if (idx < CN0 + CN1) {
        oidx = idx - CN0;
        src = wqkvg + ((size_t)oidx << 2);
        dst = wqb;
    } else if (idx < CN0 + CN1 + CN2) {
        oidx = idx - CN0 - CN1;
        src = wout + ((size_t)oidx << 2);
        dst = wob;
    } else return;
    f32x4 v = {0.f, 0.f, 0.f, 0.f};
    if (!zero_fill) v = *(const f32x4*)src;
    union { u16 h[4]; uint2 u2; } o;
#pragma unroll
    for (int i = 0; i < 4; ++i) o.h[i] = f2bf(v[i]);
    *(uint2*)(dst + ((size_t)oidx << 2)) = o.u2;
}

// ---------------- GEMM1: qkvg = x0 @ Wqkvg^T, SWAPPED operands (A=W, B=x0) ----------
// C/D layout: row = W-col d = base(mi) + (l>>4)*4 + r (4 CONTIGUOUS d per lane!),
// col = t = thalf*64 + ni*16 + (l&15). Q/K/G epilogue packs r=0..3 -> one 8B store
// (was 64 scalar 2B stores/thread). RoPE pairing on A-side frags: mi <-> mi+2 =
// d <-> d+128, pure register math; cos/sin become contiguous f32x4 loads.
// RMS denom: lane-local sum + shfl_xor(16,32) + rowsum[128][4] cross-wave exchange.
__global__ __launch_bounds__(512) void k_gemm_qkvg(const u16* __restrict__ A, const u16* __restrict__ Bm,
                                                   const float* __restrict__ cosb, const float* __restrict__ sinb,
                                                   const float* __restrict__ tao,
                                                   u16* __restrict__ Qb, u16* __restrict__ Kb,
                                                   u16* __restrict__ Vt, u16* __restrict__ Gb) {
    __shared__ __align__(16) u16 ldsW[256 * 64];      // 32KB (W tile, 256 d-rows)
    __shared__ __align__(16) u16 ldsX[128 * 64];      // 16KB (x0 tile, 128 t-rows)
    __shared__ float rowsum[128 * 4];                 // 2KB
    const int tid = threadIdx.x, l = tid & 63, w = tid >> 6;
    const int row0 = blockIdx.x * 128;                // t-tile base
    const int gcol0 = blockIdx.y * 256;               // W-col base (one head-type)
    const int h = gcol0 >> 10, ty = (gcol0 & 1023) >> 8;
    const int g = w >> 1, thalf = w & 1;              // d-group (64), t-half (64)
    f32x4 acc[4][4];                                  // [mi(d-frag)][ni(t-frag)]
    const f32x4 zero = {0.f, 0.f, 0.f, 0.f};
#pragma unroll
    for (int i = 0; i < 4; ++i)
#pragma unroll
        for (int j = 0; j < 4; ++j) acc[i][j] = zero;

    for (int kt = 0; kt < KDIM; kt += 64) {
        __syncthreads();
#pragma unroll
        for (int it = 0; it < 4; ++it) {      // W: 256 rows of 128B
            int lin = (it * 512 + tid) * 16;
            int r = lin >> 7, cb = lin & 127;
            int scb = cb ^ ((r & 7) << 4);
            GLD16((const char*)(Bm + (size_t)(gcol0 + r) * KDIM + kt) + scb,
                  (char*)ldsW + it * 8192 + w * 1024);
        }
#pragma unroll
        for (int it = 0; it < 2; ++it) {      // x0: 128 rows of 128B
            int lin = (it * 512 + tid) * 16;
            int r = lin >> 7, cb = lin & 127;
            int scb = cb ^ ((r & 7) << 4);
            GLD16((const char*)(A + (size_t)(row0 + r) * KDIM + kt) + scb,
                  (char*)ldsX + it * 8192 + w * 1024);
        }
        __syncthreads();
#pragma unroll
        for (int kk = 0; kk < 64; kk += 32) {
            bf16x8 af[4], bfr[4];
            int cbyte = (kk + ((l >> 4) << 3)) * 2;
#pragma unroll
            for (int mi = 0; mi < 4; ++mi) {   // A = W rows (paired-column map)
                int rr = g * 32 + (mi & 1) * 16 + (mi >> 1) * 128 + (l & 15);
                af[mi] = *(const bf16x8*)((const char*)ldsW + ((rr * 128 + cbyte) ^ ((rr & 7) << 4)));
            }
#pragma unroll
            for (int ni = 0; ni < 4; ++ni) {   // B = x0 rows
                int rr = thalf * 64 + ni * 16 + (l & 15);
                bfr[ni] = *(const bf16x8*)((const char*)ldsX + ((rr * 128 + cbyte) ^ ((rr & 7) << 4)));
            }
#pragma unroll
            for (int mi = 0; mi < 4; ++mi)
#pragma unroll
                for (int ni = 0; ni < 4; ++ni)
                    acc[mi][ni] = __builtin_amdgcn_mfma_f32_16x16x32_bf16(af[mi], bfr[ni], acc[mi][ni], 0, 0, 0);
        }
    }
    // ---------------- fused epilogue (in-register, packed 8B stores) ----------------
    const float eps = 1.1920928955078125e-07f;
    if (ty < 2) {
        // per-t sum of squares: lane-local over this wave's 64 d, reduce across l>>4,
        // then across the 4 d-groups via rowsum LDS
#pragma unroll
        for (int ni = 0; ni < 4; ++ni) {
            float ss = 0.f;
#pragma unroll
            for (int mi = 0; mi < 4; ++mi)
#pragma unroll
                for (int r = 0; r < 4; ++r) { float v = acc[mi][ni][r]; ss += v * v; }
            ss += __shfl_xor(ss, 16, 64);
            ss += __shfl_xor(ss, 32, 64);
            if (l < 16) {
                int trow = thalf * 64 + ni * 16 + l;
                rowsum[trow * 4 + g] = ss;
            }
        }
        __syncthreads();
        const float tv = (ty == 0) ? tao[0] * 0.0625f : tao[1];
        u16* Obuf = (ty == 0) ? Qb : Kb;
#pragma unroll
        for (int ni = 0; ni < 4; ++ni) {
            int trow = thalf * 64 + ni * 16 + (l & 15);
            int grow = row0 + trow;
            if (grow >= MREAL) continue;
            int b = grow / TT, t = grow - b * TT;
            f32x4 rsv = *(const f32x4*)(rowsum + trow * 4);
            float rs = rsv[0] + rsv[1] + rsv[2] + rsv[3];
            float scale = rsqrtf(rs * (1.0f / 256.0f) + eps) * tv;
            u16* dst = Obuf + ((size_t)((b * 8 + h) * TT + t) << 8);
#pragma unroll
            for (int mih = 0; mih < 2; ++mih) {
                int d0 = g * 32 + mih * 16 + ((l >> 4) << 2);
                f32x4 cv = *(const f32x4*)(cosb + t * 128 + d0);
                f32x4 sv = *(const f32x4*)(sinb + t * 128 + d0);
                u16x4 lo, hi;
#pragma unroll
                for (int r = 0; r < 4; ++r) {
                    float xlo = acc[mih][ni][r], xhi = acc[mih + 2][ni][r];
                    lo[r] = f2bf((xlo * cv[r] + xhi * sv[r]) * scale);
                    hi[r] = f2bf((xhi * cv[r] - xlo * sv[r]) * scale);
                }
                *(u16x4*)(dst + d0) = lo;
                *(u16x4*)(dst + d0 + 128) = hi;
            }
        }
    } else {
#pragma unroll
        for (int ni = 0; ni < 4; ++ni) {
            int trow = thalf * 64 + ni * 16 + (l & 15);
            int grow = row0 + trow;
            if (grow >= MREAL) continue;
            int b = grow / TT, t = grow - b * TT;
            int bh = b * 8 + h;
            if (ty == 3) {
                u16* dst = Gb + ((size_t)(bh * TT + t) << 8);
#pragma unroll
                for (int mi = 0; mi < 4; ++mi) {
                    int d0 = g * 32 + (mi & 1) * 16 + (mi >> 1) * 128 + ((l >> 4) << 2);
                    u16x4 pk;
#pragma unroll
                    for (int r = 0; r < 4; ++r) pk[r] = f2bf(acc[mi][ni][r]);
                    *(u16x4*)(dst + d0) = pk;
                }
            } else {
#pragma unroll
                for (int mi = 0; mi < 4; ++mi) {
                    int d0 = g * 32 + (mi & 1) * 16 + (mi >> 1) * 128 + ((l >> 4) << 2);
#pragma unroll
                    for (int r = 0; r < 4; ++r)
                        Vt[(size_t)(bh * 256 + d0 + r) * VTP + t] = f2bf(acc[mi][ni][r]);
                }
            }
        }
    }
}

// ---------------- flash attention (round-11 form: KVBLK=64 pair-cooperative) --------
__global__ __launch_bounds__(512) void k_attn(const u16* __restrict__ Qb, const u16* __restrict__ Kb,
                                              const u16* __restrict__ Vt, const u16* __restrict__ Gb,
                                              const float* __restrict__ tao,
                                              u16* __restrict__ Y) {
    __shared__ __align__(16) u16 Kt[2][64 * 256];   // 32KB each
    __shared__ __align__(16) u16 Vl[2][256 * 64];   // 32KB each
    __shared__ __align__(16) u16 Plds[8][16 * 64];  // per-GROUP P tile, swizzled; 16KB
    const int tid = threadIdx.x, l = tid & 63, w = tid >> 6;
    const int qt = 15 - (blockIdx.x >> 5);          // heavy tiles first
    const int bh = blockIdx.x & 31;                 // pinned to XCD bh%8
    const int b = bh >> 3, h = bh & 7;
    const int g0 = (w >> 1) * 2;                    // this pair's first group
    const int kvh = (w & 1) * 32;                   // QK kv-half offset
    const int dh = (w & 1) * 128;                   // PV d-half offset
    const int mq_g0 = qt * 128 + g0 * 16 + 1;       // first q-row of the pair
    const size_t qkbase = (size_t)bh * TT * 256;
    const size_t vrow0 = (size_t)bh * 256;
    const float Cs = tao[0] * tao[1] * 16.0f;       // score upper bound (rmsnorm)

    bf16x8 aq[2][8];
#pragma unroll
    for (int g = 0; g < 2; ++g) {
        int mq = mq_g0 + g * 16 + (l & 15);
        const u16* qp = Qb + qkbase + ((size_t)mq << 8) + ((l >> 4) << 3);
#pragma unroll
        for (int kk = 0; kk < 8; ++kk) aq[g][kk] = *(const bf16x8*)(qp + kk * 32);
    }
    bf16x8 vone;
#pragma unroll
    for (int i = 0; i < 8; ++i) vone[i] = (short)0x3F80;
    f32x4 acc[2][8], accs[2];
    const f32x4 zero = {0.f, 0.f, 0.f, 0.f};
#pragma unroll
    for (int g = 0; g < 2; ++g) {
#pragma unroll
        for (int i = 0; i < 8; ++i) acc[g][i] = zero;
        accs[g] = zero;
    }

    const int nkv = 2 * qt + 3;

    auto STAGE = [&](int j, int bufi) {
        const int kv0 = j << 6;
#pragma unroll
        for (int it = 0; it < 4; ++it) {
            int lin = (it * 512 + tid) * 16;
            {
                int r = lin >> 9, cbyt = lin & 511;
                int scb = cbyt ^ ((r & 7) << 4);
                int krow = kv0 + r; if (krow > 2048) krow = 2048;
                GLD16((const char*)(Kb + qkbase + ((size_t)krow << 8)) + scb,
                      (char*)&Kt[bufi][0] + it * 8192 + w * 1024);
            }
            {
                int vr = lin >> 7, cb = lin & 127;
                int scb = cb ^ ((vr & 7) << 4);
                GLD16((const char*)(Vt + (vrow0 + vr) * VTP + kv0) + scb,
                      (char*)&Vl[bufi][0] + it * 8192 + w * 1024);
            }
        }
    };

    STAGE(0, 0);
    int buf = 0;

    for (int j = 0; j < nkv; ++j) {
        const int kv0 = j << 6;
        if (j + 1 < nkv) { STAGE(j + 1, buf ^ 1); VMCNT(8); }
        else             { VMCNT(0); }
        SBAR(); MEMFENCE();

        const bool active = (kv0 <= mq_g0 + 31);
        if (active) {
            f32x4 s[2][2];
#pragma unroll
            for (int g = 0; g < 2; ++g) { s[g][0] = zero; s[g][1] = zero; }
            __builtin_amdgcn_s_setprio(1);
#pragma unroll
            for (int kk = 0; kk < 8; ++kk) {
                int cbyte = kk * 64 + ((l >> 4) << 4);
#pragma unroll
                for (int t = 0; t < 2; ++t) {
                    int rr = kvh + t * 16 + (l & 15);
                    bf16x8 bk = *(const bf16x8*)((const char*)&Kt[buf][0] + ((rr * 512 + cbyte) ^ ((rr & 7) << 4)));
#pragma unroll
                    for (int g = 0; g < 2; ++g)
                        s[g][t] = __builtin_amdgcn_mfma_f32_16x16x32_bf16(aq[g][kk], bk, s[g][t], 0, 0, 0);
                }
            }
            __builtin_amdgcn_s_setprio(0);
#pragma unroll
            for (int g = 0; g < 2; ++g) {
                char* pwb = (char*)&Plds[g0 + g][0];
                const bool needmask = (kv0 + kvh + 31 > mq_g0 + g * 16);
#pragma unroll
                for (int t = 0; t < 2; ++t)
#pragma unroll
                    for (int r = 0; r < 4; ++r) {
                        float sv = s[g][t][r];
                        if (needmask) {
                            int kg = kv0 + kvh + t * 16 + (l & 15);
                            int qg = mq_g0 + g * 16 + ((l >> 4) << 2) + r;
                            if (kg > qg) sv = -1e30f;
                        }
                        float pv = __expf(sv - Cs);
                        int row = ((l >> 4) << 2) + r;
                        int byte = row * 128 + (kvh + t * 16 + (l & 15)) * 2;
                        *(u16*)(pwb + (byte ^ ((row & 7) << 4))) = f2bf(pv);
                    }
            }
        }
        LGKMCNT0(); SBAR(); MEMFENCE();

        if (active) {
            bf16x8 ap[2][2];
#pragma unroll
            for (int g = 0; g < 2; ++g) {
                const char* prb = (const char*)&Plds[g0 + g][0];
                int row = l & 15;
                int b0 = row * 128 + ((l >> 4) << 4);
                ap[g][0] = *(const bf16x8*)(prb + (b0 ^ ((row & 7) << 4)));
                ap[g][1] = *(const bf16x8*)(prb + ((b0 + 64) ^ ((row & 7) << 4)));
            }
            __builtin_amdgcn_s_setprio(1);
#pragma unroll
            for (int df = 0; df < 8; ++df) {
                int vr = dh + df * 16 + (l & 15);
                int cbase = vr * 128 + ((l >> 4) << 4);
                bf16x8 bv0 = *(const bf16x8*)((const char*)&Vl[buf][0] + (cbase ^ ((vr & 7) << 4)));
                bf16x8 bv1 = *(const bf16x8*)((const char*)&Vl[buf][0] + ((cbase + 64) ^ ((vr & 7) << 4)));
#pragma unroll
                for (int g = 0; g < 2; ++g) {
                    acc[g][df] = __builtin_amdgcn_mfma_f32_16x16x32_bf16(ap[g][0], bv0, acc[g][df], 0, 0, 0);
                    acc[g][df] = __builtin_amdgcn_mfma_f32_16x16x32_bf16(ap[g][1], bv1, acc[g][df], 0, 0, 0);
                }
            }
#pragma unroll
            for (int g = 0; g < 2; ++g) {
                accs[g] = __builtin_amdgcn_mfma_f32_16x16x32_bf16(ap[g][0], vone, accs[g], 0, 0, 0);
                accs[g] = __builtin_amdgcn_mfma_f32_16x16x32_bf16(ap[g][1], vone, accs[g], 0, 0, 0);
            }
            __builtin_amdgcn_s_setprio(0);
        }
        MEMFENCE(); SBAR();
        buf ^= 1;
    }
#pragma unroll
    for (int g = 0; g < 2; ++g)
#pragma unroll
        for (int r = 0; r < 4; ++r) {
            int mq = mq_g0 + g * 16 + ((l >> 4) << 2) + r;
            float inv = 1.0f / accs[g][r];
            const u16* gp = Gb + qkbase + ((size_t)mq << 8) + dh + (l & 15);
            u16* yp = Y + ((size_t)(b * 2048 + mq - 1)) * 2048 + h * 256 + dh + (l & 15);
#pragma unroll
            for (int df = 0; df < 8; ++df) {
                float g2 = bf2f(gp[df * 16]);
                float sg = 1.0f / (1.0f + __expf(-g2));
                yp[df * 16] = f2bf(acc[g][df][r] * inv * sg);
            }
        }
}

// ---------------- GEMM3: out = Y @ Wout^T (round-11 form: BM=64, BN=64, 512 blocks) --
__global__ __launch_bounds__(256) void k_gemm_out(const u16* __restrict__ A, const u16* __restrict__ Bm,
                                                  float* __restrict__ Cout) {
    __shared__ __align__(16) u16 ldsA[64 * 64];
    __shared__ __align__(16) u16 ldsB[64 * 64];
    const int tid = threadIdx.x;
    const int l = tid & 63, w = tid >> 6;
    const int row0 = blockIdx.x * 64, col0 = blockIdx.y * 64;
    const int mbase = (w >> 1) * 32, nbase = (w & 1) * 32;
    const int K2 = 2048;
    f32x4 acc[2][2];
    const f32x4 zero = {0.f, 0.f, 0.f, 0.f};
#pragma unroll
    for (int i = 0; i < 2; ++i)
#pragma unroll
        for (int j = 0; j < 2; ++j) acc[i][j] = zero;

    for (int kt = 0; kt < K2; kt += 64) {
        __syncthreads();
#pragma unroll
        for (int it = 0; it < 2; ++it) {
            int lin = (it * 256 + tid) * 16;
            int r = lin >> 7;
            int cb = lin & 127;
            int scb = cb ^ ((r & 7) << 4);
            GLD16((const char*)(A + (size_t)(row0 + r) * K2 + kt) + scb,
                  (char*)ldsA + it * 4096 + w * 1024);
            GLD16((const char*)(Bm + (size_t)(col0 + r) * K2 + kt) + scb,
                  (char*)ldsB + it * 4096 + w * 1024);
        }
        __syncthreads();
#pragma unroll
        for (int kk = 0; kk < 64; kk += 32) {
            bf16x8 af[2], bfr[2];
            int cbyte = (kk + ((l >> 4) << 3)) * 2;
#pragma unroll
            for (int mi = 0; mi < 2; ++mi) {
                int rr = mbase + mi * 16 + (l & 15);
                af[mi] = *(const bf16x8*)((const char*)ldsA + ((rr * 128 + cbyte) ^ ((rr & 7) << 4)));
            }
#pragma unroll
            for (int ni = 0; ni < 2; ++ni) {
                int rr = nbase + ni * 16 + (l & 15);
                bfr[ni] = *(const bf16x8*)((const char*)ldsB + ((rr * 128 + cbyte) ^ ((rr & 7) << 4)));
            }
#pragma unroll
            for (int mi = 0; mi < 2; ++mi)
#pragma unroll
                for (int ni = 0; ni < 2; ++ni)
                    acc[mi][ni] = __builtin_amdgcn_mfma_f32_16x16x32_bf16(af[mi], bfr[ni], acc[mi][ni], 0, 0, 0);
        }
    }
#pragma unroll
    for (int mi = 0; mi < 2; ++mi)
#pragma unroll
        for (int ni = 0; ni < 2; ++ni)
#pragma unroll
            for (int r = 0; r < 4; ++r) {
                int grow = row0 + mbase + mi * 16 + ((l >> 4) << 2) + r;
                int gcol = col0 + nbase + ni * 16 + (l & 15);
                Cout[(size_t)grow * 256 + gcol] = acc[mi][ni][r];
            }
}

extern "C" void kernel_launch(void* const* d_in, const int* in_sizes, int n_in,
                              void* d_out, int out_size, void* d_ws, size_t ws_size,
                              hipStream_t stream) {
    const float* x     = (const float*)d_in[0];
    const float* cosb  = (const float*)d_in[1];
    const float* sinb  = (const float*)d_in[2];
    const float* wqkvg = (const float*)d_in[3];
    const float* wsink = (const float*)d_in[4];
    const float* wout  = (const float*)d_in[5];
    const float* tao   = (const float*)d_in[6];
    float* out = (float*)d_out;

    char* ws = (char*)d_ws;
    u16* x0b = (u16*)(ws + 0);            // 8320*256*2       = 4,259,840
    u16* wqb = (u16*)(ws + 4259840);      // 8192*256*2       = 4,194,304
    u16* wob = (u16*)(ws + 8454144);      // 256*2048*2       = 1,048,576
    u16* Qb  = (u16*)(ws + 9502720);      // 32*2049*256*2    = 33,570,816
    u16* Kb  = (u16*)(ws + 43073536);     // 33,570,816
    u16* Gb  = (u16*)(ws + 76644352);     // 33,570,816
    u16* Vt  = (u16*)(ws + 110215168);    // 32*256*2112*2    = 34,603,008
    u16* Yb  = (u16*)(ws + 144818176);    // 8192*2048*2      = 33,554,432
    // total 178,372,608 bytes

    k_conv_all<<<dim3((CN0 + CN1 + CN2 + 255) / 256), 256, 0, stream>>>(
        x, wsink, wqkvg, wout, x0b, wqb, wob);
    k_gemm_qkvg<<<dim3(65, 32), 512, 0, stream>>>(x0b, wqb, cosb, sinb, tao, Qb, Kb, Vt, Gb);
    k_attn<<<dim3(16 * 32), 512, 0, stream>>>(Qb, Kb, Vt, Gb, tao, Yb);
    k_gemm_out<<<dim3(128, 4), 256, 0, stream>>>(Yb, wob, out);
}